// Round 2
// baseline (150.925 us; speedup 1.0000x reference)
//
#include <hip/hip_runtime.h>

// NegativeSelection: score[i] = max(min_j ||x_i - s_j|| - 0.1, 0)
// N=16384, M=8192, D=128, fp32 in/out.
//
// R2 structure: one-shot LDS staging (no K/M iteration barriers).
//   Block = 128 rows x 256 cols. B-slice (256 cols x 128 k fp16 = 64 KB)
//   staged via global_load_lds ONCE, single __syncthreads, then 256 MFMAs
//   free-run. Per-row min -> global atomicMin on bias-shifted float bits.
//   acc = (b2/2 + 160) - dot  (A pre-negated; bias keeps value positive so
//   float bits are uint-ordered for atomicMin).
//
// ws: Aws fp16 [N*128] tiled [tile][k8][row][8], NEGATED   (4 MB)
//     Bws fp16 [M*128] same tiling                          (2 MB)
//     b2h f32 [M]  = 0.5*|s_j|^2                            (32 KB)
//     a2  f32 [N]  = |x_i|^2                                (64 KB)
//     Pmin u32 [N] = atomicMin target (init +inf by prep)   (64 KB)

using half_t = _Float16;
typedef _Float16 half8 __attribute__((ext_vector_type(8)));
typedef float floatx16 __attribute__((ext_vector_type(16)));

#define TILE_ELEMS (128 * 128)
#define BIAS 160.0f

__device__ __forceinline__ void async_load16(const void* g, void* l) {
    __builtin_amdgcn_global_load_lds(
        (const __attribute__((address_space(1))) void*)g,
        (__attribute__((address_space(3))) void*)l, 16, 0, 0);
}

// One block per 128x128 input tile: fp32 -> fp16 tiled [k8][row][8] (A negated),
// row norms (a2 for x, 0.5*norm for self), and Pmin init (+inf) by blocks < 64.
__global__ __launch_bounds__(256) void prep_kernel(
    const float* __restrict__ x, const float* __restrict__ self,
    half_t* __restrict__ Aws, half_t* __restrict__ Bws,
    float* __restrict__ b2h, float* __restrict__ a2,
    unsigned* __restrict__ Pmin, int Atiles)
{
    __shared__ float part[256];
    int tile = blockIdx.x;
    int tid  = threadIdx.x;
    bool isB = tile >= Atiles;
    int bt   = tile - Atiles;
    const float* src = isB ? (self + (size_t)bt * TILE_ELEMS)
                           : (x    + (size_t)tile * TILE_ELEMS);
    half_t* dst = isB ? (Bws + (size_t)bt * TILE_ELEMS)
                      : (Aws + (size_t)tile * TILE_ELEMS);
    float sgn = isB ? 1.f : -1.f;

    int rowt = tid & 127;
    int k8b  = tid >> 7;
    float ss = 0.f;
    #pragma unroll
    for (int i = 0; i < 8; ++i) {
        int k8 = i * 2 + k8b;
        const float4* p = (const float4*)(src + rowt * 128 + k8 * 8);
        float4 f0 = p[0];
        float4 f1 = p[1];
        half8 h;
        h[0] = (half_t)(sgn * f0.x); h[1] = (half_t)(sgn * f0.y);
        h[2] = (half_t)(sgn * f0.z); h[3] = (half_t)(sgn * f0.w);
        h[4] = (half_t)(sgn * f1.x); h[5] = (half_t)(sgn * f1.y);
        h[6] = (half_t)(sgn * f1.z); h[7] = (half_t)(sgn * f1.w);
        *(half8*)(dst + (size_t)(i * 256 + tid) * 8) = h;
        ss += f0.x*f0.x + f0.y*f0.y + f0.z*f0.z + f0.w*f0.w;
        ss += f1.x*f1.x + f1.y*f1.y + f1.z*f1.z + f1.w*f1.w;
    }
    part[tid] = ss;
    __syncthreads();
    if (tid < 128) {
        float s = part[tid] + part[tid + 128];
        if (isB) b2h[bt * 128 + tid]   = 0.5f * s;
        else     a2[tile * 128 + tid]  = s;
    }
    if (tile < 64) Pmin[tile * 256 + tid] = 0x7F800000u;  // +inf bits
}

// Grid (N/128, M/256). Block 256 thr = 4 waves 2x2; wave = 64 rows x 128 cols
// (two 64-col sub-blocks). A fragments in registers; whole B-slice in LDS.
__global__ __launch_bounds__(256, 2) void min_gemm_kernel(
    const half_t* __restrict__ Aws, const half_t* __restrict__ Bws,
    const float* __restrict__ b2h, unsigned* __restrict__ Pmin)
{
    __shared__ half_t Bsh[16 * 256 * 8];  // 64 KB, [k8][col 0..256][8]

    int tid  = threadIdx.x;
    int lane = tid & 63;
    int wid  = tid >> 6;
    int wr   = wid >> 1, wc = wid & 1;
    int ln31 = lane & 31, lh = lane >> 5;
    int rb = blockIdx.x, cs = blockIdx.y;

    // Stage the 64 KB B-slice (tiles 2cs, 2cs+1): 64 chunks of 1 KB.
    // LDS chunk c=k8*256+col at byte c*16; col = t*128+row. Lane-contiguous.
    const half_t* Bt0 = Bws + (size_t)(cs * 2) * TILE_ELEMS;
    #pragma unroll
    for (int j = 0; j < 16; ++j) {
        int seg  = wid * 16 + j;
        int k8   = seg >> 2;
        int t    = (seg >> 1) & 1;
        int rowb = (seg & 1) * 64;
        async_load16(Bt0 + (size_t)t * TILE_ELEMS + (size_t)(k8 * 128 + rowb + lane) * 8,
                     Bsh + (size_t)seg * 512);
    }

    // A fragments: rows wr*64 + rt*32 + ln31, k8 = ki*2+lh (global loads,
    // overlap with the LDS staging; drained by the same barrier).
    const half_t* Atile = Aws + (size_t)rb * TILE_ELEMS;
    half8 areg[2][8];
    #pragma unroll
    for (int rt = 0; rt < 2; ++rt)
        #pragma unroll
        for (int ki = 0; ki < 8; ++ki) {
            int k8  = ki * 2 + lh;
            int row = wr * 64 + rt * 32 + ln31;
            areg[rt][ki] = *(const half8*)(Atile + (size_t)(k8 * 128 + row) * 8);
        }

    float minacc[2][16];
    #pragma unroll
    for (int rt = 0; rt < 2; ++rt)
        #pragma unroll
        for (int r = 0; r < 16; ++r) minacc[rt][r] = 1e30f;

    __syncthreads();   // the ONLY barrier: B staged + areg loads drained

    #pragma unroll
    for (int cb = 0; cb < 2; ++cb) {
        int colb = wc * 128 + cb * 64;          // within the 256-col slice
        int gcol = cs * 256 + colb + ln31;
        float b2v0 = b2h[gcol]      + BIAS;
        float b2v1 = b2h[gcol + 32] + BIAS;

        floatx16 acc[2][2];
        #pragma unroll
        for (int r = 0; r < 16; ++r) {
            acc[0][0][r] = b2v0; acc[0][1][r] = b2v1;
            acc[1][0][r] = b2v0; acc[1][1][r] = b2v1;
        }

        #pragma unroll
        for (int ki = 0; ki < 8; ++ki) {
            int k8 = ki * 2 + lh;
            half8 bf0 = *(const half8*)(Bsh + (size_t)(k8 * 256 + colb + ln31) * 8);
            half8 bf1 = *(const half8*)(Bsh + (size_t)(k8 * 256 + colb + 32 + ln31) * 8);
            acc[0][0] = __builtin_amdgcn_mfma_f32_32x32x16_f16(areg[0][ki], bf0, acc[0][0], 0, 0, 0);
            acc[0][1] = __builtin_amdgcn_mfma_f32_32x32x16_f16(areg[0][ki], bf1, acc[0][1], 0, 0, 0);
            acc[1][0] = __builtin_amdgcn_mfma_f32_32x32x16_f16(areg[1][ki], bf0, acc[1][0], 0, 0, 0);
            acc[1][1] = __builtin_amdgcn_mfma_f32_32x32x16_f16(areg[1][ki], bf1, acc[1][1], 0, 0, 0);
        }

        #pragma unroll
        for (int rt = 0; rt < 2; ++rt)
            #pragma unroll
            for (int r = 0; r < 16; ++r) {
                float v = fminf(acc[rt][0][r], acc[rt][1][r]);
                minacc[rt][r] = fminf(minacc[rt][r], v);
            }
    }

    // Min over the 32 col-lanes, then device-scope atomicMin (biased-positive
    // floats are monotone as uints). C/D row = (r&3) + 8*(r>>2) + 4*lh.
    #pragma unroll
    for (int rt = 0; rt < 2; ++rt)
        #pragma unroll
        for (int r = 0; r < 16; ++r) {
            float v = minacc[rt][r];
            #pragma unroll
            for (int m = 1; m < 32; m <<= 1)
                v = fminf(v, __shfl_xor(v, m, 64));
            if (ln31 == 0) {
                int row = rb * 128 + wr * 64 + rt * 32
                        + (r & 3) + 8 * (r >> 2) + 4 * lh;
                atomicMin(&Pmin[row], __float_as_uint(v));
            }
        }
}

// Elementwise: d2 = a2 + 2*(pmin - BIAS); score = max(sqrt(max(d2,0)) - 0.1, 0)
__global__ __launch_bounds__(256) void final_kernel(
    const float* __restrict__ a2, const unsigned* __restrict__ Pmin,
    float* __restrict__ out)
{
    int i = blockIdx.x * 256 + threadIdx.x;
    float p  = __uint_as_float(Pmin[i]) - BIAS;
    float d2 = a2[i] + 2.f * p;
    out[i] = fmaxf(sqrtf(fmaxf(d2, 0.f)) - 0.1f, 0.f);
}

extern "C" void kernel_launch(void* const* d_in, const int* in_sizes, int n_in,
                              void* d_out, int out_size, void* d_ws, size_t ws_size,
                              hipStream_t stream)
{
    const float* x    = (const float*)d_in[0];
    const float* self = (const float*)d_in[1];
    float* out        = (float*)d_out;

    int N = in_sizes[0] / 128;   // 16384
    int M = in_sizes[1] / 128;   // 8192
    int Atiles = N / 128;        // 128
    int Btiles = M / 128;        // 64

    char* w        = (char*)d_ws;
    half_t* Aws    = (half_t*)w;
    half_t* Bws    = Aws + (size_t)N * 128;
    float*  b2h    = (float*)(w + (size_t)(N + M) * 128 * 2);
    float*  a2     = b2h + M;
    unsigned* Pmin = (unsigned*)(a2 + N);
    // ws: 4 MB + 2 MB + 32 KB + 64 KB + 64 KB ≈ 6.2 MB

    prep_kernel<<<Atiles + Btiles, 256, 0, stream>>>(x, self, Aws, Bws, b2h, a2, Pmin, Atiles);

    dim3 grid(Atiles, M / 256);  // 128 x 32 = 4096 blocks, 2 resident/CU
    min_gemm_kernel<<<grid, 256, 0, stream>>>(Aws, Bws, b2h, Pmin);

    final_kernel<<<N / 256, 256, 0, stream>>>(a2, Pmin, out);
}

// Round 4
// 110.745 us; speedup vs baseline: 1.3628x; 1.3628x over previous
//
#include <hip/hip_runtime.h>

// NegativeSelection: score[i] = max(min_j ||x_i - s_j|| - 0.1, 0)
// N=16384, M=8192, D=128, fp32 in/out.
//
// R4 = R3 with the partial-min race fixed: slot key must include the
// column-wave (wc), since wc=0/1 reduce DIFFERENT 64-col halves.
// Pmin[row*12 + s*2 + wc]; final mins 12 slots.
//
// ws: Aws fp16 [N*128] tiled [tile][k8][row][8], NEGATED   (4 MB)
//     Bws fp16 [M*128] same tiling                          (2 MB)
//     b2h f32 [M]  = 0.5*|s_j|^2                            (32 KB)
//     a2  f32 [N]  = |x_i|^2                                (64 KB)
//     Pmin f32 [N*12] partial mins (6 slices x 2 col-waves) (768 KB)

using half_t = _Float16;
typedef _Float16 half8 __attribute__((ext_vector_type(8)));
typedef float floatx16 __attribute__((ext_vector_type(16)));

#define TILE_ELEMS (128 * 128)

__device__ __forceinline__ void async_load16(const void* g, void* l) {
    __builtin_amdgcn_global_load_lds(
        (const __attribute__((address_space(1))) void*)g,
        (__attribute__((address_space(3))) void*)l, 16, 0, 0);
}

// Block = 64-row half-tile. Blocks [0,256): x -> Aws (negated) + a2.
// Blocks [256,384): self -> Bws + b2h.
__global__ __launch_bounds__(256) void prep_kernel(
    const float* __restrict__ x, const float* __restrict__ self,
    half_t* __restrict__ Aws, half_t* __restrict__ Bws,
    float* __restrict__ b2h, float* __restrict__ a2)
{
    __shared__ float part[256];
    int bid = blockIdx.x, tid = threadIdx.x;
    bool isB = bid >= 256;
    int lb = isB ? (bid - 256) : bid;          // local half-tile index
    const float* src = (isB ? self : x) + (size_t)lb * (64 * 128);
    int tile = lb >> 1, h = lb & 1;
    half_t* dstT = (isB ? Bws : Aws) + (size_t)tile * TILE_ELEMS;
    float sgn = isB ? 1.f : -1.f;

    int r = tid & 63;
    float ss = 0.f;
    #pragma unroll
    for (int i = 0; i < 4; ++i) {
        int k8 = i * 4 + (tid >> 6);
        const float4* p = (const float4*)(src + r * 128 + k8 * 8);
        float4 f0 = p[0], f1 = p[1];
        half8 hv;
        hv[0] = (half_t)(sgn * f0.x); hv[1] = (half_t)(sgn * f0.y);
        hv[2] = (half_t)(sgn * f0.z); hv[3] = (half_t)(sgn * f0.w);
        hv[4] = (half_t)(sgn * f1.x); hv[5] = (half_t)(sgn * f1.y);
        hv[6] = (half_t)(sgn * f1.z); hv[7] = (half_t)(sgn * f1.w);
        *(half8*)(dstT + (size_t)(k8 * 128 + h * 64 + r) * 8) = hv;
        ss += f0.x*f0.x + f0.y*f0.y + f0.z*f0.z + f0.w*f0.w;
        ss += f1.x*f1.x + f1.y*f1.y + f1.z*f1.z + f1.w*f1.w;
    }
    part[tid] = ss;
    __syncthreads();
    if (tid < 64) {
        float s = part[tid] + part[tid + 64] + part[tid + 128] + part[tid + 192];
        int grow = lb * 64 + tid;
        if (isB) b2h[grow] = 0.5f * s;
        else     a2[grow]  = s;
    }
}

// Grid (128 row-blocks, 6 M-slices) = 768 = exactly 3 blocks/CU, LB(256,3).
// Block 256 thr = 4 waves 2x2; wave = 64 rows x 64 cols per 128-col tile,
// looping over the slice's 10-11 tiles.
__global__ __launch_bounds__(256, 3) void min_gemm_kernel(
    const half_t* __restrict__ Aws, const half_t* __restrict__ Bws,
    const float* __restrict__ b2h, float* __restrict__ Pmin)
{
    __shared__ half_t Bsh[TILE_ELEMS];  // 32 KB, [k8][row][8]

    int tid  = threadIdx.x;
    int lane = tid & 63;
    int wid  = tid >> 6;
    int wr   = wid >> 1, wc = wid & 1;
    int ln31 = lane & 31, lh = lane >> 5;
    int rb = blockIdx.x, s = blockIdx.y;

    // Uneven slice bounds over 64 tiles: [s*32/3, (s+1)*32/3)
    int t0 = (s * 32) / 3;
    int t1 = ((s + 1) * 32) / 3;

    // A fragments: rows wr*64 + rt*32 + ln31, k8 = ki*2 + lh.
    const half_t* Atile = Aws + (size_t)rb * TILE_ELEMS;
    half8 areg[2][8];
    #pragma unroll
    for (int rt = 0; rt < 2; ++rt)
        #pragma unroll
        for (int ki = 0; ki < 8; ++ki) {
            int k8  = ki * 2 + lh;
            int row = wr * 64 + rt * 32 + ln31;
            areg[rt][ki] = *(const half8*)(Atile + (size_t)(k8 * 128 + row) * 8);
        }

    float minacc[2][16];
    #pragma unroll
    for (int rt = 0; rt < 2; ++rt)
        #pragma unroll
        for (int r = 0; r < 16; ++r) minacc[rt][r] = 1e30f;

    for (int it = t0; it < t1; ++it) {
        const half_t* Bt = Bws + (size_t)it * TILE_ELEMS;
        __syncthreads();  // WAR: previous iter's reads done
        #pragma unroll
        for (int j = 0; j < 8; ++j) {
            int seg = wid * 8 + j;                 // 0..31, each 1 KB
            async_load16(Bt + (size_t)(seg * 64 + lane) * 8,
                         Bsh + (size_t)seg * 512);
        }
        __syncthreads();  // staged

        int gcol = it * 128 + wc * 64 + ln31;
        float b2v0 = b2h[gcol];
        float b2v1 = b2h[gcol + 32];

        floatx16 acc[2][2];
        #pragma unroll
        for (int r = 0; r < 16; ++r) {
            acc[0][0][r] = b2v0; acc[0][1][r] = b2v1;
            acc[1][0][r] = b2v0; acc[1][1][r] = b2v1;
        }

        #pragma unroll
        for (int ki = 0; ki < 8; ++ki) {
            int k8 = ki * 2 + lh;
            half8 bf0 = *(const half8*)(Bsh + (size_t)(k8 * 128 + wc * 64 + ln31) * 8);
            half8 bf1 = *(const half8*)(Bsh + (size_t)(k8 * 128 + wc * 64 + 32 + ln31) * 8);
            acc[0][0] = __builtin_amdgcn_mfma_f32_32x32x16_f16(areg[0][ki], bf0, acc[0][0], 0, 0, 0);
            acc[0][1] = __builtin_amdgcn_mfma_f32_32x32x16_f16(areg[0][ki], bf1, acc[0][1], 0, 0, 0);
            acc[1][0] = __builtin_amdgcn_mfma_f32_32x32x16_f16(areg[1][ki], bf0, acc[1][0], 0, 0, 0);
            acc[1][1] = __builtin_amdgcn_mfma_f32_32x32x16_f16(areg[1][ki], bf1, acc[1][1], 0, 0, 0);
        }

        #pragma unroll
        for (int rt = 0; rt < 2; ++rt)
            #pragma unroll
            for (int r = 0; r < 16; ++r) {
                float v = fminf(acc[rt][0][r], acc[rt][1][r]);
                minacc[rt][r] = fminf(minacc[rt][r], v);
            }
    }

    // Min across 32 col-lanes; C/D row = (r&3) + 8*(r>>2) + 4*lh.
    // Slot key MUST include wc: the two column-waves reduce different cols.
    #pragma unroll
    for (int rt = 0; rt < 2; ++rt)
        #pragma unroll
        for (int r = 0; r < 16; ++r) {
            float v = minacc[rt][r];
            #pragma unroll
            for (int m = 1; m < 32; m <<= 1)
                v = fminf(v, __shfl_xor(v, m, 64));
            if (ln31 == 0) {
                int row = rb * 128 + wr * 64 + rt * 32
                        + (r & 3) + 8 * (r >> 2) + 4 * lh;
                Pmin[(size_t)row * 12 + s * 2 + wc] = v;
            }
        }
}

// Thread per row: min of 12 partials, d2 = a2 + 2*pmin, sqrt/shift/clamp.
__global__ __launch_bounds__(256) void final_kernel(
    const float* __restrict__ a2, const float* __restrict__ Pmin,
    float* __restrict__ out)
{
    int i = blockIdx.x * 256 + threadIdx.x;
    const float4* p4 = (const float4*)(Pmin + (size_t)i * 12);
    float4 q0 = p4[0], q1 = p4[1], q2 = p4[2];
    float m = fminf(fminf(fminf(q0.x, q0.y), fminf(q0.z, q0.w)),
             fminf(fminf(fminf(q1.x, q1.y), fminf(q1.z, q1.w)),
                   fminf(fminf(q2.x, q2.y), fminf(q2.z, q2.w))));
    float d2 = a2[i] + 2.f * m;
    out[i] = fmaxf(sqrtf(fmaxf(d2, 0.f)) - 0.1f, 0.f);
}

extern "C" void kernel_launch(void* const* d_in, const int* in_sizes, int n_in,
                              void* d_out, int out_size, void* d_ws, size_t ws_size,
                              hipStream_t stream)
{
    const float* x    = (const float*)d_in[0];
    const float* self = (const float*)d_in[1];
    float* out        = (float*)d_out;

    int N = in_sizes[0] / 128;   // 16384
    int M = in_sizes[1] / 128;   // 8192

    char* w      = (char*)d_ws;
    half_t* Aws  = (half_t*)w;
    half_t* Bws  = Aws + (size_t)N * 128;
    float*  b2h  = (float*)(w + (size_t)(N + M) * 128 * 2);
    float*  a2   = b2h + M;
    float*  Pmin = a2 + N;
    // ws: 4 MB + 2 MB + 32 KB + 64 KB + 768 KB ≈ 6.9 MB

    prep_kernel<<<(N + M) / 64, 256, 0, stream>>>(x, self, Aws, Bws, b2h, a2);

    dim3 grid(N / 128, 6);       // 768 blocks = exactly 3/CU
    min_gemm_kernel<<<grid, 256, 0, stream>>>(Aws, Bws, b2h, Pmin);

    final_kernel<<<N / 256, 256, 0, stream>>>(a2, Pmin, out);
}